// Round 9
// baseline (95.530 us; speedup 1.0000x reference)
//
#include <hip/hip_runtime.h>

constexpr int kN = 8, kC = 128, kH = 64, kW = 64, kO = 128;
constexpr int kHW = kH * kW;

typedef float f32x4 __attribute__((ext_vector_type(4)));
typedef short bf16x8 __attribute__((ext_vector_type(8)));
typedef unsigned short ushort8 __attribute__((ext_vector_type(8)));

__device__ __forceinline__ float bf2f(unsigned short u) {
  unsigned int x = ((unsigned int)u) << 16;
  return __builtin_bit_cast(float, x);
}
__device__ __forceinline__ unsigned short f2bf(float f) {
  unsigned int b = __builtin_bit_cast(unsigned int, f);
  b += 0x7FFFu + ((b >> 16) & 1u);  // RNE
  return (unsigned short)(b >> 16);
}

// ============================================================================
// prep (+ folded weight reorder): VERBATIM (verified passing R7/R8).
// ============================================================================
__global__ __launch_bounds__(256) void prep_kernel(
    const float* __restrict__ inp, const float* __restrict__ ste_w,
    const float* __restrict__ ste_b, const float* __restrict__ bn_g,
    const float* __restrict__ bn_b, const float* __restrict__ bn_m,
    const float* __restrict__ bn_v, unsigned short* __restrict__ nhwc,
    float* __restrict__ prm, const float* __restrict__ dw,
    unsigned short* __restrict__ wkb) {
  const int bid = blockIdx.x;
  if (bid >= kN * kH) {  // ---- folded reorder branch (block-uniform) ----
    int idx = (bid - kN * kH) * 256 + threadIdx.x;
    if (idx < 9 * kO * kC) {
      int k = idx / (kO * kC);
      int r = idx - k * (kO * kC);
      int o = r >> 7, c = r & 127;
      wkb[idx] = f2bf(dw[(o * kC + c) * 9 + k]);
    }
    return;
  }

  __shared__ float tile[kC * kW];     // [c][w], 32 KB
  __shared__ float part[4][3][kW];    // partial dots
  const int tid = threadIdx.x;
  const int nh = bid;
  const int n = nh >> 6, h = nh & 63;
  const float* base = inp + (size_t)n * kC * kHW + h * kW;

  for (int i = tid; i < kC * kW; i += 256) {
    int c = i >> 6, w = i & 63;
    tile[i] = base[c * kHW + w];
  }
  __syncthreads();

  {
    const int w = tid & 63, cg = tid >> 6;
    float s0 = 0.f, s1 = 0.f, s2 = 0.f;
#pragma unroll 8
    for (int j = 0; j < 32; ++j) {
      int c = cg * 32 + j;
      float v = tile[c * kW + w];
      s0 += v * ste_w[c];
      s1 += v * ste_w[kC + c];
      s2 += v * ste_w[2 * kC + c];
    }
    part[cg][0][w] = s0;
    part[cg][1][w] = s1;
    part[cg][2][w] = s2;
  }
  __syncthreads();
  if (tid < kW) {
    const int w = tid;
    float s0 = part[0][0][w] + part[1][0][w] + part[2][0][w] + part[3][0][w];
    float s1 = part[0][1][w] + part[1][1][w] + part[2][1][w] + part[3][1][w];
    float s2 = part[0][2][w] + part[1][2][w] + part[2][2][w] + part[3][2][w];
    s0 = (s0 + ste_b[0] - bn_m[0]) * (bn_g[0] * rsqrtf(bn_v[0] + 1e-5f)) + bn_b[0];
    s1 = (s1 + ste_b[1] - bn_m[1]) * (bn_g[1] * rsqrtf(bn_v[1] + 1e-5f)) + bn_b[1];
    s2 = (s2 + ste_b[2] - bn_m[2]) * (bn_g[2] * rsqrtf(bn_v[2] + 1e-5f)) + bn_b[2];
    float th = tanhf(s0) * (3.14f / 6.0f);
    float i1 = tanhf(s1) * 0.75f + 0.75f;
    float i2 = tanhf(s2) * 0.75f + 0.75f;
    float sn = sinf(th), cs = cosf(th);
    prm[nh * 192 + w * 3 + 0] = cs * i1;  // a00
    prm[nh * 192 + w * 3 + 1] = sn;       // sin
    prm[nh * 192 + w * 3 + 2] = cs * i2;  // a11
  }

  for (int i = tid; i < kW * 16; i += 256) {
    int w = i & 63, ch = i >> 6;
    int c0 = ch * 8;
    ushort8 v;
#pragma unroll
    for (int j = 0; j < 8; ++j) v[j] = f2bf(tile[(c0 + j) * kW + w]);
    *(ushort8*)&nhwc[((size_t)(n * kH + h) * kW + w) * kC + c0] = v;
  }
}

// ============================================================================
// MFMA main kernel: block = (n,h,w-half). M=32, N=128, K=9x128. R6-verified
// geometry (8 waves = 2mg x 4ng, acc[2], 16x16x32). ONE change vs R6:
// B LDS staging ELIMINATED — B fragments live in registers, double-buffered
// across taps (load B(k+1) global->reg while MFMA(k) consumes B(k) regs).
// Addresses = same bytes the old LDS round-trip delivered (R7-verified).
// Barrier now guards only the 8 KB A tile; LDS 80 KB -> 16 KB.
// ============================================================================
__global__ __launch_bounds__(512, 4) void deform_mfma_kernel(
    const unsigned short* __restrict__ nhwc,
    const unsigned short* __restrict__ wkb,
    const float* __restrict__ prm, const float* __restrict__ db,
    float* __restrict__ out) {
  __shared__ __align__(16) unsigned short As[2][32 * 128];  // 2 x 8 KB

  const int tid = threadIdx.x;
  const int lane = tid & 63, wave = tid >> 6;
  const int nh = blockIdx.x >> 1;
  const int w0 = (blockIdx.x & 1) << 5;
  const int n = nh >> 6, h = nh & 63;
  const unsigned short* nhwc_n = nhwc + (size_t)n * kH * kW * kC;

  // ---- per-thread A-build assignment & params (p fixed per thread) ----
  const int p = tid >> 4, ch = tid & 15;
  const int cb = ch * 8;
  const float a00 = prm[nh * 192 + (w0 + p) * 3 + 0];
  const float sn  = prm[nh * 192 + (w0 + p) * 3 + 1];
  const float a11 = prm[nh * 192 + (w0 + p) * 3 + 2];

  const int mg = wave >> 2, ng = wave & 3;  // 2 M-groups x 4 N-groups
  const int row = mg * 16 + (lane & 15);
  const int kq = lane >> 4;
  const int rsw = (row & 7) << 4;
  f32x4 acc[2];
  acc[0] = (f32x4){0.f, 0.f, 0.f, 0.f};
  acc[1] = (f32x4){0.f, 0.f, 0.f, 0.f};

  // ---- B fragment base pointers (R7-verified addressing) ----
  const int orow0 = (ng * 2 + 0) * 16 + (lane & 15);
  const int orow1 = (ng * 2 + 1) * 16 + (lane & 15);
  const char* B0 = (const char*)wkb + orow0 * 256 + kq * 16;
  const char* B1 = (const char*)wkb + orow1 * 256 + kq * 16;

  bf16x8 bbuf[2][2][4];  // [buf][frag][ks] — all indices compile-time
  ushort8 aC[4];         // A corners in flight
  float wgt[4];          // bilinear weights in flight

  auto load_B = [&](int k, int buf) {
#pragma unroll
    for (int ks = 0; ks < 4; ++ks) {
      bbuf[buf][0][ks] = *(const bf16x8*)(B0 + k * 32768 + ks * 64);
      bbuf[buf][1][ks] = *(const bf16x8*)(B1 + k * 32768 + ks * 64);
    }
  };

  auto gather_A = [&](int k) {  // R6-verified math
    const float fdy = (float)(k / 3 - 1);
    const float fdx = (float)(k % 3 - 1);
    const float o0 = fdy;
    const float o1 = (k == 2) ? -1.0f : fdx;  // OFF row 2 duplicates row 0
    float y = (float)h + fdy + o0 * a00 + o1 * sn;
    float x = (float)(w0 + p) + fdx - o0 * sn + o1 * a11;
    float y0f = floorf(y), x0f = floorf(x);
    float wy = y - y0f, wx = x - x0f;
    int y0 = (int)y0f, x0 = (int)x0f;
    bool yv0 = (unsigned)y0 < (unsigned)kH;
    bool yv1 = (unsigned)(y0 + 1) < (unsigned)kH;
    bool xv0 = (unsigned)x0 < (unsigned)kW;
    bool xv1 = (unsigned)(x0 + 1) < (unsigned)kW;
    int y0c = min(max(y0, 0), kH - 1);
    int y1c = min(max(y0 + 1, 0), kH - 1);
    int x0c = min(max(x0, 0), kW - 1);
    int x1c = min(max(x0 + 1, 0), kW - 1);
    wgt[0] = (1.f - wy) * (1.f - wx) * (yv0 && xv0 ? 1.f : 0.f);
    wgt[1] = (1.f - wy) * wx * (yv0 && xv1 ? 1.f : 0.f);
    wgt[2] = wy * (1.f - wx) * (yv1 && xv0 ? 1.f : 0.f);
    wgt[3] = wy * wx * (yv1 && xv1 ? 1.f : 0.f);
    aC[0] = *(const ushort8*)&nhwc_n[((y0c * kW) + x0c) * kC + cb];
    aC[1] = *(const ushort8*)&nhwc_n[((y0c * kW) + x1c) * kC + cb];
    aC[2] = *(const ushort8*)&nhwc_n[((y1c * kW) + x0c) * kC + cb];
    aC[3] = *(const ushort8*)&nhwc_n[((y1c * kW) + x1c) * kC + cb];
  };

  auto write_A = [&](int buf) {  // interp -> swizzled As (R6-verified layout)
    ushort8 r;
#pragma unroll
    for (int j = 0; j < 8; ++j) {
      float val = bf2f(aC[0][j]) * wgt[0] + bf2f(aC[1][j]) * wgt[1] +
                  bf2f(aC[2][j]) * wgt[2] + bf2f(aC[3][j]) * wgt[3];
      r[j] = f2bf(val);
    }
    *(ushort8*)((char*)As[buf] + p * 256 + ((ch * 16) ^ ((p & 7) << 4))) = r;
  };

  // ---- prologue: tap 0 ----
  gather_A(0);
  load_B(0, 0);
  write_A(0);
  __syncthreads();

  // ---- pipelined tap loop (fully unrolled; one barrier per tap) ----
#pragma unroll
  for (int k = 0; k < 9; ++k) {
    const int cur = k & 1;
    if (k < 8) {
      gather_A(k + 1);        // A corners in flight during MFMA
      load_B(k + 1, cur ^ 1); // B(k+1) regs in flight during MFMA
    }

    const char* Ab = (const char*)As[cur] + row * 256;
#pragma unroll
    for (int ks = 0; ks < 4; ++ks) {
      bf16x8 a = *(const bf16x8*)(Ab + ((ks * 64 + kq * 16) ^ rsw));
      acc[0] = __builtin_amdgcn_mfma_f32_16x16x32_bf16(a, bbuf[cur][0][ks],
                                                       acc[0], 0, 0, 0);
      acc[1] = __builtin_amdgcn_mfma_f32_16x16x32_bf16(a, bbuf[cur][1][ks],
                                                       acc[1], 0, 0, 0);
    }

    if (k < 8) write_A(cur ^ 1);
    __syncthreads();
  }

  // ---- epilogue (round-4 verified mapping) ----
  const int pixb = mg * 16 + (lane >> 4) * 4;
#pragma unroll
  for (int f = 0; f < 2; ++f) {
    const int o = (ng * 2 + f) * 16 + (lane & 15);
    const float bias = db[o];
    float4 v = {acc[f][0] + bias, acc[f][1] + bias, acc[f][2] + bias,
                acc[f][3] + bias};
    *(float4*)&out[((size_t)(n * kO + o)) * kHW + h * kW + w0 + pixb] = v;
  }
}

// ============================================================================
// Fallback (fp32, no workspace) — verbatim.
// ============================================================================
__global__ __launch_bounds__(256) void deform_kernel_f32(
    const float* __restrict__ inp, const float* __restrict__ ste_w,
    const float* __restrict__ ste_b, const float* __restrict__ bn_g,
    const float* __restrict__ bn_b, const float* __restrict__ bn_m,
    const float* __restrict__ bn_v, const float* __restrict__ dw,
    const float* __restrict__ db, float* __restrict__ out) {
  __shared__ __align__(16) float smp[kC * 16];
  __shared__ float prm[16][3];
  const int tid = threadIdx.x;
  const int base = blockIdx.x * 16;
  const int n = base / kHW;
  const int hw = base - n * kHW;
  const int h = hw / kW;
  const int w0 = hw - h * kW;
  const float* inp_n = inp + (size_t)n * kC * kHW;

  for (int i = tid; i < kC * 16; i += 256) {
    int c = i >> 4, p = i & 15;
    smp[i] = inp_n[c * kHW + h * kW + w0 + p];
  }
  __syncthreads();
  {
    const int p = tid >> 4, cl = tid & 15;
    float a0 = 0.f, a1 = 0.f, a2 = 0.f;
#pragma unroll
    for (int i = 0; i < 8; ++i) {
      int c = cl + (i << 4);
      float v = smp[c * 16 + p];
      a0 += v * ste_w[c];
      a1 += v * ste_w[kC + c];
      a2 += v * ste_w[2 * kC + c];
    }
#pragma unroll
    for (int off = 8; off; off >>= 1) {
      a0 += __shfl_down(a0, off, 16);
      a1 += __shfl_down(a1, off, 16);
      a2 += __shfl_down(a2, off, 16);
    }
    if (cl == 0) {
      float s0 = (a0 + ste_b[0] - bn_m[0]) * (bn_g[0] * rsqrtf(bn_v[0] + 1e-5f)) + bn_b[0];
      float s1 = (a1 + ste_b[1] - bn_m[1]) * (bn_g[1] * rsqrtf(bn_v[1] + 1e-5f)) + bn_b[1];
      float s2 = (a2 + ste_b[2] - bn_m[2]) * (bn_g[2] * rsqrtf(bn_v[2] + 1e-5f)) + bn_b[2];
      float th = tanhf(s0) * (3.14f / 6.0f);
      float i1 = tanhf(s1) * 0.75f + 0.75f;
      float i2 = tanhf(s2) * 0.75f + 0.75f;
      prm[p][0] = cosf(th) * i1;
      prm[p][1] = sinf(th);
      prm[p][2] = cosf(th) * i2;
    }
  }
  const int o = tid & 127;
  const int ph = tid >> 7;
  float acc[8] = {0.f};
  for (int k = 0; k < 9; ++k) {
    __syncthreads();
    const float fdy = (float)(k / 3 - 1);
    const float fdx = (float)(k % 3 - 1);
    const float o0 = fdy;
    const float o1 = (k == 2) ? -1.0f : fdx;
    for (int i = tid; i < kC * 16; i += 256) {
      int c = i >> 4, p = i & 15;
      float a00 = prm[p][0], sn = prm[p][1], a11 = prm[p][2];
      float y = (float)h + fdy + o0 * a00 + o1 * sn;
      float x = (float)(w0 + p) + fdx - o0 * sn + o1 * a11;
      float y0f = floorf(y), x0f = floorf(x);
      float wy = y - y0f, wx = x - x0f;
      int y0 = (int)y0f, x0 = (int)x0f;
      const float* ic = inp_n + c * kHW;
      bool yv0 = (unsigned)y0 < (unsigned)kH;
      bool yv1 = (unsigned)(y0 + 1) < (unsigned)kH;
      bool xv0 = (unsigned)x0 < (unsigned)kW;
      bool xv1 = (unsigned)(x0 + 1) < (unsigned)kW;
      int y0c = min(max(y0, 0), kH - 1);
      int y1c = min(max(y0 + 1, 0), kH - 1);
      int x0c = min(max(x0, 0), kW - 1);
      int x1c = min(max(x0 + 1, 0), kW - 1);
      float v00 = (yv0 && xv0) ? ic[y0c * kW + x0c] : 0.f;
      float v01 = (yv0 && xv1) ? ic[y0c * kW + x1c] : 0.f;
      float v10 = (yv1 && xv0) ? ic[y1c * kW + x0c] : 0.f;
      float v11 = (yv1 && xv1) ? ic[y1c * kW + x1c] : 0.f;
      smp[i] = v00 * (1.f - wy) * (1.f - wx) + v01 * (1.f - wy) * wx +
               v10 * wy * (1.f - wx) + v11 * wy * wx;
    }
    __syncthreads();
    const float* wp = dw + (size_t)o * kC * 9 + k;
#pragma unroll 4
    for (int c = 0; c < kC; ++c) {
      float wv = wp[(size_t)c * 9];
      const float4 s0 = *(const float4*)&smp[c * 16 + (ph << 3)];
      const float4 s1 = *(const float4*)&smp[c * 16 + (ph << 3) + 4];
      acc[0] += wv * s0.x; acc[1] += wv * s0.y; acc[2] += wv * s0.z; acc[3] += wv * s0.w;
      acc[4] += wv * s1.x; acc[5] += wv * s1.y; acc[6] += wv * s1.z; acc[7] += wv * s1.w;
    }
  }
  const float bias = db[o];
  float* op = out + ((size_t)(n * kO + o)) * kHW + h * kW + w0 + (ph << 3);
#pragma unroll
  for (int j = 0; j < 8; ++j) op[j] = acc[j] + bias;
}

extern "C" void kernel_launch(void* const* d_in, const int* in_sizes, int n_in,
                              void* d_out, int out_size, void* d_ws, size_t ws_size,
                              hipStream_t stream) {
  const float* inp   = (const float*)d_in[0];
  const float* ste_w = (const float*)d_in[1];
  const float* ste_b = (const float*)d_in[2];
  const float* bn_g  = (const float*)d_in[3];
  const float* bn_b  = (const float*)d_in[4];
  const float* bn_m  = (const float*)d_in[5];
  const float* bn_v  = (const float*)d_in[6];
  const float* dw    = (const float*)d_in[7];
  const float* db    = (const float*)d_in[8];
  float* out = (float*)d_out;

  const size_t nhwc_bytes = (size_t)kN * kH * kW * kC * 2;
  const size_t wkb_bytes = (size_t)9 * kO * kC * 2;
  const size_t prm_bytes = (size_t)kN * kH * kW * 3 * 4;
  const size_t need = nhwc_bytes + wkb_bytes + prm_bytes;

  if (ws_size >= need) {
    unsigned short* nhwc = (unsigned short*)d_ws;
    unsigned short* wkb = (unsigned short*)((char*)d_ws + nhwc_bytes);
    float* prm = (float*)((char*)d_ws + nhwc_bytes + wkb_bytes);
    const int reorder_blocks = (9 * kO * kC + 255) / 256;  // 576
    prep_kernel<<<kN * kH + reorder_blocks, 256, 0, stream>>>(
        inp, ste_w, ste_b, bn_g, bn_b, bn_m, bn_v, nhwc, prm, dw, wkb);
    deform_mfma_kernel<<<kN * kH * 2, 512, 0, stream>>>(nhwc, wkb, prm, db, out);
  } else {
    deform_kernel_f32<<<kN * kHW / 16, 256, 0, stream>>>(
        inp, ste_w, ste_b, bn_g, bn_b, bn_m, bn_v, dw, db, out);
  }
}

// Round 11
// 51.659 us; speedup vs baseline: 1.8492x; 1.8492x over previous
//
#include <hip/hip_runtime.h>

constexpr int kN = 8, kC = 128, kH = 64, kW = 64, kO = 128;
constexpr int kHW = kH * kW;

typedef float f32x4 __attribute__((ext_vector_type(4)));
typedef short bf16x8 __attribute__((ext_vector_type(8)));
typedef unsigned short ushort8 __attribute__((ext_vector_type(8)));

__device__ __forceinline__ float bf2f(unsigned short u) {
  unsigned int x = ((unsigned int)u) << 16;
  return __builtin_bit_cast(float, x);
}
__device__ __forceinline__ unsigned short f2bf(float f) {
  unsigned int b = __builtin_bit_cast(unsigned int, f);
  b += 0x7FFFu + ((b >> 16) & 1u);  // RNE
  return (unsigned short)(b >> 16);
}

#define GLOAD_LDS16(g, l)                                              \
  __builtin_amdgcn_global_load_lds(                                    \
      (const __attribute__((address_space(1))) void*)(g),              \
      (__attribute__((address_space(3))) void*)(l), 16, 0, 0)

// ============================================================================
// prep (+ folded weight reorder): prep body VERBATIM (verified R7/R8/R9).
// Reorder branch: wkb stored PRE-SWIZZLED (16B chunk c8 of row o lands at
// chunk c8 ^ (o&7)) so a LINEAR global_load_lds DMA yields exactly the
// swizzled LDS image R6's staged path built; MFMA B-reads unchanged.
// ============================================================================
__global__ __launch_bounds__(256) void prep_kernel(
    const float* __restrict__ inp, const float* __restrict__ ste_w,
    const float* __restrict__ ste_b, const float* __restrict__ bn_g,
    const float* __restrict__ bn_b, const float* __restrict__ bn_m,
    const float* __restrict__ bn_v, unsigned short* __restrict__ nhwc,
    float* __restrict__ prm, const float* __restrict__ dw,
    unsigned short* __restrict__ wkb) {
  const int bid = blockIdx.x;
  if (bid >= kN * kH) {  // ---- folded reorder branch (block-uniform) ----
    int idx = (bid - kN * kH) * 256 + threadIdx.x;
    if (idx < 9 * kO * kC) {
      int k = idx / (kO * kC);
      int r = idx - k * (kO * kC);
      int o = r >> 7, c = r & 127;
      int c8 = c >> 3;
      int dstc = ((c8 ^ (o & 7)) << 3) | (c & 7);  // pre-swizzled slot
      wkb[k * (kO * kC) + (o << 7) + dstc] = f2bf(dw[(o * kC + c) * 9 + k]);
    }
    return;
  }

  __shared__ float tile[kC * kW];     // [c][w], 32 KB
  __shared__ float part[4][3][kW];    // partial dots
  const int tid = threadIdx.x;
  const int nh = bid;
  const int n = nh >> 6, h = nh & 63;
  const float* base = inp + (size_t)n * kC * kHW + h * kW;

  for (int i = tid; i < kC * kW; i += 256) {
    int c = i >> 6, w = i & 63;
    tile[i] = base[c * kHW + w];
  }
  __syncthreads();

  {
    const int w = tid & 63, cg = tid >> 6;
    float s0 = 0.f, s1 = 0.f, s2 = 0.f;
#pragma unroll 8
    for (int j = 0; j < 32; ++j) {
      int c = cg * 32 + j;
      float v = tile[c * kW + w];
      s0 += v * ste_w[c];
      s1 += v * ste_w[kC + c];
      s2 += v * ste_w[2 * kC + c];
    }
    part[cg][0][w] = s0;
    part[cg][1][w] = s1;
    part[cg][2][w] = s2;
  }
  __syncthreads();
  if (tid < kW) {
    const int w = tid;
    float s0 = part[0][0][w] + part[1][0][w] + part[2][0][w] + part[3][0][w];
    float s1 = part[0][1][w] + part[1][1][w] + part[2][1][w] + part[3][1][w];
    float s2 = part[0][2][w] + part[1][2][w] + part[2][2][w] + part[3][2][w];
    s0 = (s0 + ste_b[0] - bn_m[0]) * (bn_g[0] * rsqrtf(bn_v[0] + 1e-5f)) + bn_b[0];
    s1 = (s1 + ste_b[1] - bn_m[1]) * (bn_g[1] * rsqrtf(bn_v[1] + 1e-5f)) + bn_b[1];
    s2 = (s2 + ste_b[2] - bn_m[2]) * (bn_g[2] * rsqrtf(bn_v[2] + 1e-5f)) + bn_b[2];
    float th = tanhf(s0) * (3.14f / 6.0f);
    float i1 = tanhf(s1) * 0.75f + 0.75f;
    float i2 = tanhf(s2) * 0.75f + 0.75f;
    float sn = sinf(th), cs = cosf(th);
    prm[nh * 192 + w * 3 + 0] = cs * i1;  // a00
    prm[nh * 192 + w * 3 + 1] = sn;       // sin
    prm[nh * 192 + w * 3 + 2] = cs * i2;  // a11
  }

  for (int i = tid; i < kW * 16; i += 256) {
    int w = i & 63, ch = i >> 6;
    int c0 = ch * 8;
    ushort8 v;
#pragma unroll
    for (int j = 0; j < 8; ++j) v[j] = f2bf(tile[(c0 + j) * kW + w]);
    *(ushort8*)&nhwc[((size_t)(n * kH + h) * kW + w) * kC + c0] = v;
  }
}

// ============================================================================
// MFMA main kernel: R6-verified skeleton (block = (n,h,w-half), M=32, N=128,
// 8 waves = 2mg x 4ng, acc[2], dbuf As/Bs, 1 barrier/tap). ONE change vs R6:
// B staged by global_load_lds DMA (linear dest; wkb pre-swizzled) — no reg
// round-trip, no ds_writes, immune to compiler load-sinking (R9 failure).
// A gather/interp/write path byte-identical to R6.
// ============================================================================
__global__ __launch_bounds__(512, 4) void deform_mfma_kernel(
    const unsigned short* __restrict__ nhwc,
    const unsigned short* __restrict__ wkb,
    const float* __restrict__ prm, const float* __restrict__ db,
    float* __restrict__ out) {
  __shared__ __align__(16) unsigned short As[2][32 * 128];   // 2 x 8 KB
  __shared__ __align__(16) unsigned short Bs[2][128 * 128];  // 2 x 32 KB

  const int tid = threadIdx.x;
  const int lane = tid & 63, wave = tid >> 6;
  const int nh = blockIdx.x >> 1;
  const int w0 = (blockIdx.x & 1) << 5;
  const int n = nh >> 6, h = nh & 63;
  const unsigned short* nhwc_n = nhwc + (size_t)n * kH * kW * kC;

  // ---- per-thread A-build assignment & params (p fixed per thread) ----
  const int p = tid >> 4, ch = tid & 15;
  const int cb = ch * 8;
  const float a00 = prm[nh * 192 + (w0 + p) * 3 + 0];
  const float sn  = prm[nh * 192 + (w0 + p) * 3 + 1];
  const float a11 = prm[nh * 192 + (w0 + p) * 3 + 2];

  const int mg = wave >> 2, ng = wave & 3;  // 2 M-groups x 4 N-groups
  const int row = mg * 16 + (lane & 15);
  const int kq = lane >> 4;
  const int rsw = (row & 7) << 4;
  f32x4 acc[2];
  acc[0] = (f32x4){0.f, 0.f, 0.f, 0.f};
  acc[1] = (f32x4){0.f, 0.f, 0.f, 0.f};

  ushort8 aC[4];  // A corners in flight
  float wgt[4];   // bilinear weights in flight

  // ---- B staging: 4 DMA ops/wave, fully linear 32 KB copy ----
  auto issue_B = [&](int k, int buf) {
    const char* gk = (const char*)wkb + (size_t)k * 32768;
    char* lb = (char*)Bs[buf];
    const int wo = wave * 1024;
    const int lo16 = lane * 16;
#pragma unroll
    for (int it = 0; it < 4; ++it) {
      GLOAD_LDS16(gk + it * 8192 + wo + lo16, lb + it * 8192 + wo);
    }
  };

  auto gather_A = [&](int k) {  // R6-verified math
    const float fdy = (float)(k / 3 - 1);
    const float fdx = (float)(k % 3 - 1);
    const float o0 = fdy;
    const float o1 = (k == 2) ? -1.0f : fdx;  // OFF row 2 duplicates row 0
    float y = (float)h + fdy + o0 * a00 + o1 * sn;
    float x = (float)(w0 + p) + fdx - o0 * sn + o1 * a11;
    float y0f = floorf(y), x0f = floorf(x);
    float wy = y - y0f, wx = x - x0f;
    int y0 = (int)y0f, x0 = (int)x0f;
    bool yv0 = (unsigned)y0 < (unsigned)kH;
    bool yv1 = (unsigned)(y0 + 1) < (unsigned)kH;
    bool xv0 = (unsigned)x0 < (unsigned)kW;
    bool xv1 = (unsigned)(x0 + 1) < (unsigned)kW;
    int y0c = min(max(y0, 0), kH - 1);
    int y1c = min(max(y0 + 1, 0), kH - 1);
    int x0c = min(max(x0, 0), kW - 1);
    int x1c = min(max(x0 + 1, 0), kW - 1);
    wgt[0] = (1.f - wy) * (1.f - wx) * (yv0 && xv0 ? 1.f : 0.f);
    wgt[1] = (1.f - wy) * wx * (yv0 && xv1 ? 1.f : 0.f);
    wgt[2] = wy * (1.f - wx) * (yv1 && xv0 ? 1.f : 0.f);
    wgt[3] = wy * wx * (yv1 && xv1 ? 1.f : 0.f);
    aC[0] = *(const ushort8*)&nhwc_n[((y0c * kW) + x0c) * kC + cb];
    aC[1] = *(const ushort8*)&nhwc_n[((y0c * kW) + x1c) * kC + cb];
    aC[2] = *(const ushort8*)&nhwc_n[((y1c * kW) + x0c) * kC + cb];
    aC[3] = *(const ushort8*)&nhwc_n[((y1c * kW) + x1c) * kC + cb];
  };

  auto write_A = [&](int buf) {  // interp -> swizzled As (R6-verified layout)
    ushort8 r;
#pragma unroll
    for (int j = 0; j < 8; ++j) {
      float val = bf2f(aC[0][j]) * wgt[0] + bf2f(aC[1][j]) * wgt[1] +
                  bf2f(aC[2][j]) * wgt[2] + bf2f(aC[3][j]) * wgt[3];
      r[j] = f2bf(val);
    }
    *(ushort8*)((char*)As[buf] + p * 256 + ((ch * 16) ^ ((p & 7) << 4))) = r;
  };

  // ---- prologue: tap 0 ----
  issue_B(0, 0);
  gather_A(0);
  write_A(0);
  __syncthreads();

  // ---- pipelined tap loop: one barrier per tap (R6 structure) ----
  for (int k = 0; k < 9; ++k) {
    const int cur = k & 1;
    if (k < 8) {
      gather_A(k + 1);          // A corners in flight during MFMA
      issue_B(k + 1, cur ^ 1);  // B DMA in flight during MFMA
    }

    const char* Ab = (const char*)As[cur] + row * 256;
    const char* Bb = (const char*)Bs[cur];
#pragma unroll
    for (int ks = 0; ks < 4; ++ks) {
      const int kb = ks * 64 + kq * 16;
      bf16x8 a = *(const bf16x8*)(Ab + (kb ^ rsw));
#pragma unroll
      for (int f = 0; f < 2; ++f) {
        const int orow = (ng * 2 + f) * 16 + (lane & 15);
        bf16x8 b = *(const bf16x8*)(Bb + orow * 256 + (kb ^ ((orow & 7) << 4)));
        acc[f] = __builtin_amdgcn_mfma_f32_16x16x32_bf16(a, b, acc[f], 0, 0, 0);
      }
    }

    if (k < 8) write_A(cur ^ 1);
    __syncthreads();
  }

  // ---- epilogue (round-4 verified mapping) ----
  const int pixb = mg * 16 + (lane >> 4) * 4;
#pragma unroll
  for (int f = 0; f < 2; ++f) {
    const int o = (ng * 2 + f) * 16 + (lane & 15);
    const float bias = db[o];
    float4 v = {acc[f][0] + bias, acc[f][1] + bias, acc[f][2] + bias,
                acc[f][3] + bias};
    *(float4*)&out[((size_t)(n * kO + o)) * kHW + h * kW + w0 + pixb] = v;
  }
}

// ============================================================================
// Fallback (fp32, no workspace) — verbatim.
// ============================================================================
__global__ __launch_bounds__(256) void deform_kernel_f32(
    const float* __restrict__ inp, const float* __restrict__ ste_w,
    const float* __restrict__ ste_b, const float* __restrict__ bn_g,
    const float* __restrict__ bn_b, const float* __restrict__ bn_m,
    const float* __restrict__ bn_v, const float* __restrict__ dw,
    const float* __restrict__ db, float* __restrict__ out) {
  __shared__ __align__(16) float smp[kC * 16];
  __shared__ float prm[16][3];
  const int tid = threadIdx.x;
  const int base = blockIdx.x * 16;
  const int n = base / kHW;
  const int hw = base - n * kHW;
  const int h = hw / kW;
  const int w0 = hw - h * kW;
  const float* inp_n = inp + (size_t)n * kC * kHW;

  for (int i = tid; i < kC * 16; i += 256) {
    int c = i >> 4, p = i & 15;
    smp[i] = inp_n[c * kHW + h * kW + w0 + p];
  }
  __syncthreads();
  {
    const int p = tid >> 4, cl = tid & 15;
    float a0 = 0.f, a1 = 0.f, a2 = 0.f;
#pragma unroll
    for (int i = 0; i < 8; ++i) {
      int c = cl + (i << 4);
      float v = smp[c * 16 + p];
      a0 += v * ste_w[c];
      a1 += v * ste_w[kC + c];
      a2 += v * ste_w[2 * kC + c];
    }
#pragma unroll
    for (int off = 8; off; off >>= 1) {
      a0 += __shfl_down(a0, off, 16);
      a1 += __shfl_down(a1, off, 16);
      a2 += __shfl_down(a2, off, 16);
    }
    if (cl == 0) {
      float s0 = (a0 + ste_b[0] - bn_m[0]) * (bn_g[0] * rsqrtf(bn_v[0] + 1e-5f)) + bn_b[0];
      float s1 = (a1 + ste_b[1] - bn_m[1]) * (bn_g[1] * rsqrtf(bn_v[1] + 1e-5f)) + bn_b[1];
      float s2 = (a2 + ste_b[2] - bn_m[2]) * (bn_g[2] * rsqrtf(bn_v[2] + 1e-5f)) + bn_b[2];
      float th = tanhf(s0) * (3.14f / 6.0f);
      float i1 = tanhf(s1) * 0.75f + 0.75f;
      float i2 = tanhf(s2) * 0.75f + 0.75f;
      prm[p][0] = cosf(th) * i1;
      prm[p][1] = sinf(th);
      prm[p][2] = cosf(th) * i2;
    }
  }
  const int o = tid & 127;
  const int ph = tid >> 7;
  float acc[8] = {0.f};
  for (int k = 0; k < 9; ++k) {
    __syncthreads();
    const float fdy = (float)(k / 3 - 1);
    const float fdx = (float)(k % 3 - 1);
    const float o0 = fdy;
    const float o1 = (k == 2) ? -1.0f : fdx;
    for (int i = tid; i < kC * 16; i += 256) {
      int c = i >> 4, p = i & 15;
      float a00 = prm[p][0], sn = prm[p][1], a11 = prm[p][2];
      float y = (float)h + fdy + o0 * a00 + o1 * sn;
      float x = (float)(w0 + p) + fdx - o0 * sn + o1 * a11;
      float y0f = floorf(y), x0f = floorf(x);
      float wy = y - y0f, wx = x - x0f;
      int y0 = (int)y0f, x0 = (int)x0f;
      const float* ic = inp_n + c * kHW;
      bool yv0 = (unsigned)y0 < (unsigned)kH;
      bool yv1 = (unsigned)(y0 + 1) < (unsigned)kH;
      bool xv0 = (unsigned)x0 < (unsigned)kW;
      bool xv1 = (unsigned)(x0 + 1) < (unsigned)kW;
      int y0c = min(max(y0, 0), kH - 1);
      int y1c = min(max(y0 + 1, 0), kH - 1);
      int x0c = min(max(x0, 0), kW - 1);
      int x1c = min(max(x0 + 1, 0), kW - 1);
      float v00 = (yv0 && xv0) ? ic[y0c * kW + x0c] : 0.f;
      float v01 = (yv0 && xv1) ? ic[y0c * kW + x1c] : 0.f;
      float v10 = (yv1 && xv0) ? ic[y1c * kW + x0c] : 0.f;
      float v11 = (yv1 && xv1) ? ic[y1c * kW + x1c] : 0.f;
      smp[i] = v00 * (1.f - wy) * (1.f - wx) + v01 * (1.f - wy) * wx +
               v10 * wy * (1.f - wx) + v11 * wy * wx;
    }
    __syncthreads();
    const float* wp = dw + (size_t)o * kC * 9 + k;
#pragma unroll 4
    for (int c = 0; c < kC; ++c) {
      float wv = wp[(size_t)c * 9];
      const float4 s0 = *(const float4*)&smp[c * 16 + (ph << 3)];
      const float4 s1 = *(const float4*)&smp[c * 16 + (ph << 3) + 4];
      acc[0] += wv * s0.x; acc[1] += wv * s0.y; acc[2] += wv * s0.z; acc[3] += wv * s0.w;
      acc[4] += wv * s1.x; acc[5] += wv * s1.y; acc[6] += wv * s1.z; acc[7] += wv * s1.w;
    }
  }
  const float bias = db[o];
  float* op = out + ((size_t)(n * kO + o)) * kHW + h * kW + w0 + (ph << 3);
#pragma unroll
  for (int j = 0; j < 8; ++j) op[j] = acc[j] + bias;
}

extern "C" void kernel_launch(void* const* d_in, const int* in_sizes, int n_in,
                              void* d_out, int out_size, void* d_ws, size_t ws_size,
                              hipStream_t stream) {
  const float* inp   = (const float*)d_in[0];
  const float* ste_w = (const float*)d_in[1];
  const float* ste_b = (const float*)d_in[2];
  const float* bn_g  = (const float*)d_in[3];
  const float* bn_b  = (const float*)d_in[4];
  const float* bn_m  = (const float*)d_in[5];
  const float* bn_v  = (const float*)d_in[6];
  const float* dw    = (const float*)d_in[7];
  const float* db    = (const float*)d_in[8];
  float* out = (float*)d_out;

  const size_t nhwc_bytes = (size_t)kN * kH * kW * kC * 2;
  const size_t wkb_bytes = (size_t)9 * kO * kC * 2;
  const size_t prm_bytes = (size_t)kN * kH * kW * 3 * 4;
  const size_t need = nhwc_bytes + wkb_bytes + prm_bytes;

  if (ws_size >= need) {
    unsigned short* nhwc = (unsigned short*)d_ws;
    unsigned short* wkb = (unsigned short*)((char*)d_ws + nhwc_bytes);
    float* prm = (float*)((char*)d_ws + nhwc_bytes + wkb_bytes);
    const int reorder_blocks = (9 * kO * kC + 255) / 256;  // 576
    prep_kernel<<<kN * kH + reorder_blocks, 256, 0, stream>>>(
        inp, ste_w, ste_b, bn_g, bn_b, bn_m, bn_v, nhwc, prm, dw, wkb);
    deform_mfma_kernel<<<kN * kH * 2, 512, 0, stream>>>(nhwc, wkb, prm, db, out);
  } else {
    deform_kernel_f32<<<kN * kHW / 16, 256, 0, stream>>>(
        inp, ste_w, ste_b, bn_g, bn_b, bn_m, bn_v, dw, db, out);
  }
}

// Round 12
// 48.657 us; speedup vs baseline: 1.9633x; 1.0617x over previous
//
#include <hip/hip_runtime.h>

constexpr int kN = 8, kC = 128, kH = 64, kW = 64, kO = 128;
constexpr int kHW = kH * kW;
constexpr int kTS = 65;  // padded tile stride (floats) — kills bank conflicts

typedef float f32x4 __attribute__((ext_vector_type(4)));
typedef short bf16x8 __attribute__((ext_vector_type(8)));
typedef unsigned short ushort8 __attribute__((ext_vector_type(8)));

__device__ __forceinline__ float bf2f(unsigned short u) {
  unsigned int x = ((unsigned int)u) << 16;
  return __builtin_bit_cast(float, x);
}
__device__ __forceinline__ unsigned short f2bf(float f) {
  unsigned int b = __builtin_bit_cast(unsigned int, f);
  b += 0x7FFFu + ((b >> 16) & 1u);  // RNE
  return (unsigned short)(b >> 16);
}

#define GLOAD_LDS16(g, l)                                              \
  __builtin_amdgcn_global_load_lds(                                    \
      (const __attribute__((address_space(1))) void*)(g),              \
      (__attribute__((address_space(3))) void*)(l), 16, 0, 0)

// ============================================================================
// prep (+ folded weight reorder). CHANGES vs R11 (this round's single
// variable, both in the NHWC path only):
//  (1) tile padded to stride 65 floats (bank-conflict break for (2));
//  (2) NHWC write loop re-indexed: 16 consecutive lanes cover the 16
//      channel-chunks of ONE pixel -> 256B-contiguous coalesced stores
//      (was: lane-per-pixel -> 64 cache lines per wave, 16x write amp).
// Values written are bit-identical; params path logic unchanged.
// ============================================================================
__global__ __launch_bounds__(256) void prep_kernel(
    const float* __restrict__ inp, const float* __restrict__ ste_w,
    const float* __restrict__ ste_b, const float* __restrict__ bn_g,
    const float* __restrict__ bn_b, const float* __restrict__ bn_m,
    const float* __restrict__ bn_v, unsigned short* __restrict__ nhwc,
    float* __restrict__ prm, const float* __restrict__ dw,
    unsigned short* __restrict__ wkb) {
  const int bid = blockIdx.x;
  if (bid >= kN * kH) {  // ---- folded reorder branch (block-uniform) ----
    int idx = (bid - kN * kH) * 256 + threadIdx.x;
    if (idx < 9 * kO * kC) {
      int k = idx / (kO * kC);
      int r = idx - k * (kO * kC);
      int o = r >> 7, c = r & 127;
      int c8 = c >> 3;
      int dstc = ((c8 ^ (o & 7)) << 3) | (c & 7);  // pre-swizzled slot
      wkb[k * (kO * kC) + (o << 7) + dstc] = f2bf(dw[(o * kC + c) * 9 + k]);
    }
    return;
  }

  __shared__ float tile[kC * kTS];    // [c][w] padded, ~33 KB
  __shared__ float part[4][3][kW];    // partial dots
  const int tid = threadIdx.x;
  const int nh = bid;
  const int n = nh >> 6, h = nh & 63;
  const float* base = inp + (size_t)n * kC * kHW + h * kW;

  for (int i = tid; i < kC * kW; i += 256) {
    int c = i >> 6, w = i & 63;
    tile[c * kTS + w] = base[c * kHW + w];
  }
  __syncthreads();

  {
    const int w = tid & 63, cg = tid >> 6;
    float s0 = 0.f, s1 = 0.f, s2 = 0.f;
#pragma unroll 8
    for (int j = 0; j < 32; ++j) {
      int c = cg * 32 + j;
      float v = tile[c * kTS + w];
      s0 += v * ste_w[c];
      s1 += v * ste_w[kC + c];
      s2 += v * ste_w[2 * kC + c];
    }
    part[cg][0][w] = s0;
    part[cg][1][w] = s1;
    part[cg][2][w] = s2;
  }
  __syncthreads();
  if (tid < kW) {
    const int w = tid;
    float s0 = part[0][0][w] + part[1][0][w] + part[2][0][w] + part[3][0][w];
    float s1 = part[0][1][w] + part[1][1][w] + part[2][1][w] + part[3][1][w];
    float s2 = part[0][2][w] + part[1][2][w] + part[2][2][w] + part[3][2][w];
    s0 = (s0 + ste_b[0] - bn_m[0]) * (bn_g[0] * rsqrtf(bn_v[0] + 1e-5f)) + bn_b[0];
    s1 = (s1 + ste_b[1] - bn_m[1]) * (bn_g[1] * rsqrtf(bn_v[1] + 1e-5f)) + bn_b[1];
    s2 = (s2 + ste_b[2] - bn_m[2]) * (bn_g[2] * rsqrtf(bn_v[2] + 1e-5f)) + bn_b[2];
    float th = tanhf(s0) * (3.14f / 6.0f);
    float i1 = tanhf(s1) * 0.75f + 0.75f;
    float i2 = tanhf(s2) * 0.75f + 0.75f;
    float sn = sinf(th), cs = cosf(th);
    prm[nh * 192 + w * 3 + 0] = cs * i1;  // a00
    prm[nh * 192 + w * 3 + 1] = sn;       // sin
    prm[nh * 192 + w * 3 + 2] = cs * i2;  // a11
  }

  // ---- NHWC bf16 write: coalesced (ch fastest across lanes) ----
  for (int i = tid; i < kW * 16; i += 256) {
    int ch = i & 15, w = i >> 4;
    int c0 = ch * 8;
    ushort8 v;
#pragma unroll
    for (int j = 0; j < 8; ++j) v[j] = f2bf(tile[(c0 + j) * kTS + w]);
    *(ushort8*)&nhwc[((size_t)(n * kH + h) * kW + w) * kC + c0] = v;
  }
}

// ============================================================================
// MFMA main kernel: VERBATIM R11 (verified, 51.66 µs). Block = (n,h,w-half),
// M=32, N=128, 8 waves = 2mg x 4ng, acc[2], dbuf As/Bs, 1 barrier/tap,
// B staged by global_load_lds DMA (linear dest; wkb pre-swizzled).
// ============================================================================
__global__ __launch_bounds__(512, 4) void deform_mfma_kernel(
    const unsigned short* __restrict__ nhwc,
    const unsigned short* __restrict__ wkb,
    const float* __restrict__ prm, const float* __restrict__ db,
    float* __restrict__ out) {
  __shared__ __align__(16) unsigned short As[2][32 * 128];   // 2 x 8 KB
  __shared__ __align__(16) unsigned short Bs[2][128 * 128];  // 2 x 32 KB

  const int tid = threadIdx.x;
  const int lane = tid & 63, wave = tid >> 6;
  const int nh = blockIdx.x >> 1;
  const int w0 = (blockIdx.x & 1) << 5;
  const int n = nh >> 6, h = nh & 63;
  const unsigned short* nhwc_n = nhwc + (size_t)n * kH * kW * kC;

  // ---- per-thread A-build assignment & params (p fixed per thread) ----
  const int p = tid >> 4, ch = tid & 15;
  const int cb = ch * 8;
  const float a00 = prm[nh * 192 + (w0 + p) * 3 + 0];
  const float sn  = prm[nh * 192 + (w0 + p) * 3 + 1];
  const float a11 = prm[nh * 192 + (w0 + p) * 3 + 2];

  const int mg = wave >> 2, ng = wave & 3;  // 2 M-groups x 4 N-groups
  const int row = mg * 16 + (lane & 15);
  const int kq = lane >> 4;
  const int rsw = (row & 7) << 4;
  f32x4 acc[2];
  acc[0] = (f32x4){0.f, 0.f, 0.f, 0.f};
  acc[1] = (f32x4){0.f, 0.f, 0.f, 0.f};

  ushort8 aC[4];  // A corners in flight
  float wgt[4];   // bilinear weights in flight

  // ---- B staging: 4 DMA ops/wave, fully linear 32 KB copy ----
  auto issue_B = [&](int k, int buf) {
    const char* gk = (const char*)wkb + (size_t)k * 32768;
    char* lb = (char*)Bs[buf];
    const int wo = wave * 1024;
    const int lo16 = lane * 16;
#pragma unroll
    for (int it = 0; it < 4; ++it) {
      GLOAD_LDS16(gk + it * 8192 + wo + lo16, lb + it * 8192 + wo);
    }
  };

  auto gather_A = [&](int k) {  // R6-verified math
    const float fdy = (float)(k / 3 - 1);
    const float fdx = (float)(k % 3 - 1);
    const float o0 = fdy;
    const float o1 = (k == 2) ? -1.0f : fdx;  // OFF row 2 duplicates row 0
    float y = (float)h + fdy + o0 * a00 + o1 * sn;
    float x = (float)(w0 + p) + fdx - o0 * sn + o1 * a11;
    float y0f = floorf(y), x0f = floorf(x);
    float wy = y - y0f, wx = x - x0f;
    int y0 = (int)y0f, x0 = (int)x0f;
    bool yv0 = (unsigned)y0 < (unsigned)kH;
    bool yv1 = (unsigned)(y0 + 1) < (unsigned)kH;
    bool xv0 = (unsigned)x0 < (unsigned)kW;
    bool xv1 = (unsigned)(x0 + 1) < (unsigned)kW;
    int y0c = min(max(y0, 0), kH - 1);
    int y1c = min(max(y0 + 1, 0), kH - 1);
    int x0c = min(max(x0, 0), kW - 1);
    int x1c = min(max(x0 + 1, 0), kW - 1);
    wgt[0] = (1.f - wy) * (1.f - wx) * (yv0 && xv0 ? 1.f : 0.f);
    wgt[1] = (1.f - wy) * wx * (yv0 && xv1 ? 1.f : 0.f);
    wgt[2] = wy * (1.f - wx) * (yv1 && xv0 ? 1.f : 0.f);
    wgt[3] = wy * wx * (yv1 && xv1 ? 1.f : 0.f);
    aC[0] = *(const ushort8*)&nhwc_n[((y0c * kW) + x0c) * kC + cb];
    aC[1] = *(const ushort8*)&nhwc_n[((y0c * kW) + x1c) * kC + cb];
    aC[2] = *(const ushort8*)&nhwc_n[((y1c * kW) + x0c) * kC + cb];
    aC[3] = *(const ushort8*)&nhwc_n[((y1c * kW) + x1c) * kC + cb];
  };

  auto write_A = [&](int buf) {  // interp -> swizzled As (R6-verified layout)
    ushort8 r;
#pragma unroll
    for (int j = 0; j < 8; ++j) {
      float val = bf2f(aC[0][j]) * wgt[0] + bf2f(aC[1][j]) * wgt[1] +
                  bf2f(aC[2][j]) * wgt[2] + bf2f(aC[3][j]) * wgt[3];
      r[j] = f2bf(val);
    }
    *(ushort8*)((char*)As[buf] + p * 256 + ((ch * 16) ^ ((p & 7) << 4))) = r;
  };

  // ---- prologue: tap 0 ----
  issue_B(0, 0);
  gather_A(0);
  write_A(0);
  __syncthreads();

  // ---- pipelined tap loop: one barrier per tap (R6 structure) ----
  for (int k = 0; k < 9; ++k) {
    const int cur = k & 1;
    if (k < 8) {
      gather_A(k + 1);          // A corners in flight during MFMA
      issue_B(k + 1, cur ^ 1);  // B DMA in flight during MFMA
    }

    const char* Ab = (const char*)As[cur] + row * 256;
    const char* Bb = (const char*)Bs[cur];
#pragma unroll
    for (int ks = 0; ks < 4; ++ks) {
      const int kb = ks * 64 + kq * 16;
      bf16x8 a = *(const bf16x8*)(Ab + (kb ^ rsw));
#pragma unroll
      for (int f = 0; f < 2; ++f) {
        const int orow = (ng * 2 + f) * 16 + (lane & 15);
        bf16x8 b = *(const bf16x8*)(Bb + orow * 256 + (kb ^ ((orow & 7) << 4)));
        acc[f] = __builtin_amdgcn_mfma_f32_16x16x32_bf16(a, b, acc[f], 0, 0, 0);
      }
    }

    if (k < 8) write_A(cur ^ 1);
    __syncthreads();
  }

  // ---- epilogue (round-4 verified mapping) ----
  const int pixb = mg * 16 + (lane >> 4) * 4;
#pragma unroll
  for (int f = 0; f < 2; ++f) {
    const int o = (ng * 2 + f) * 16 + (lane & 15);
    const float bias = db[o];
    float4 v = {acc[f][0] + bias, acc[f][1] + bias, acc[f][2] + bias,
                acc[f][3] + bias};
    *(float4*)&out[((size_t)(n * kO + o)) * kHW + h * kW + w0 + pixb] = v;
  }
}

// ============================================================================
// Fallback (fp32, no workspace) — verbatim.
// ============================================================================
__global__ __launch_bounds__(256) void deform_kernel_f32(
    const float* __restrict__ inp, const float* __restrict__ ste_w,
    const float* __restrict__ ste_b, const float* __restrict__ bn_g,
    const float* __restrict__ bn_b, const float* __restrict__ bn_m,
    const float* __restrict__ bn_v, const float* __restrict__ dw,
    const float* __restrict__ db, float* __restrict__ out) {
  __shared__ __align__(16) float smp[kC * 16];
  __shared__ float prm[16][3];
  const int tid = threadIdx.x;
  const int base = blockIdx.x * 16;
  const int n = base / kHW;
  const int hw = base - n * kHW;
  const int h = hw / kW;
  const int w0 = hw - h * kW;
  const float* inp_n = inp + (size_t)n * kC * kHW;

  for (int i = tid; i < kC * 16; i += 256) {
    int c = i >> 4, p = i & 15;
    smp[i] = inp_n[c * kHW + h * kW + w0 + p];
  }
  __syncthreads();
  {
    const int p = tid >> 4, cl = tid & 15;
    float a0 = 0.f, a1 = 0.f, a2 = 0.f;
#pragma unroll
    for (int i = 0; i < 8; ++i) {
      int c = cl + (i << 4);
      float v = smp[c * 16 + p];
      a0 += v * ste_w[c];
      a1 += v * ste_w[kC + c];
      a2 += v * ste_w[2 * kC + c];
    }
#pragma unroll
    for (int off = 8; off; off >>= 1) {
      a0 += __shfl_down(a0, off, 16);
      a1 += __shfl_down(a1, off, 16);
      a2 += __shfl_down(a2, off, 16);
    }
    if (cl == 0) {
      float s0 = (a0 + ste_b[0] - bn_m[0]) * (bn_g[0] * rsqrtf(bn_v[0] + 1e-5f)) + bn_b[0];
      float s1 = (a1 + ste_b[1] - bn_m[1]) * (bn_g[1] * rsqrtf(bn_v[1] + 1e-5f)) + bn_b[1];
      float s2 = (a2 + ste_b[2] - bn_m[2]) * (bn_g[2] * rsqrtf(bn_v[2] + 1e-5f)) + bn_b[2];
      float th = tanhf(s0) * (3.14f / 6.0f);
      float i1 = tanhf(s1) * 0.75f + 0.75f;
      float i2 = tanhf(s2) * 0.75f + 0.75f;
      prm[p][0] = cosf(th) * i1;
      prm[p][1] = sinf(th);
      prm[p][2] = cosf(th) * i2;
    }
  }
  const int o = tid & 127;
  const int ph = tid >> 7;
  float acc[8] = {0.f};
  for (int k = 0; k < 9; ++k) {
    __syncthreads();
    const float fdy = (float)(k / 3 - 1);
    const float fdx = (float)(k % 3 - 1);
    const float o0 = fdy;
    const float o1 = (k == 2) ? -1.0f : fdx;
    for (int i = tid; i < kC * 16; i += 256) {
      int c = i >> 4, p = i & 15;
      float a00 = prm[p][0], sn = prm[p][1], a11 = prm[p][2];
      float y = (float)h + fdy + o0 * a00 + o1 * sn;
      float x = (float)(w0 + p) + fdx - o0 * sn + o1 * a11;
      float y0f = floorf(y), x0f = floorf(x);
      float wy = y - y0f, wx = x - x0f;
      int y0 = (int)y0f, x0 = (int)x0f;
      const float* ic = inp_n + c * kHW;
      bool yv0 = (unsigned)y0 < (unsigned)kH;
      bool yv1 = (unsigned)(y0 + 1) < (unsigned)kH;
      bool xv0 = (unsigned)x0 < (unsigned)kW;
      bool xv1 = (unsigned)(x0 + 1) < (unsigned)kW;
      int y0c = min(max(y0, 0), kH - 1);
      int y1c = min(max(y0 + 1, 0), kH - 1);
      int x0c = min(max(x0, 0), kW - 1);
      int x1c = min(max(x0 + 1, 0), kW - 1);
      float v00 = (yv0 && xv0) ? ic[y0c * kW + x0c] : 0.f;
      float v01 = (yv0 && xv1) ? ic[y0c * kW + x1c] : 0.f;
      float v10 = (yv1 && xv0) ? ic[y1c * kW + x0c] : 0.f;
      float v11 = (yv1 && xv1) ? ic[y1c * kW + x1c] : 0.f;
      smp[i] = v00 * (1.f - wy) * (1.f - wx) + v01 * (1.f - wy) * wx +
               v10 * wy * (1.f - wx) + v11 * wy * wx;
    }
    __syncthreads();
    const float* wp = dw + (size_t)o * kC * 9 + k;
#pragma unroll 4
    for (int c = 0; c < kC; ++c) {
      float wv = wp[(size_t)c * 9];
      const float4 s0 = *(const float4*)&smp[c * 16 + (ph << 3)];
      const float4 s1 = *(const float4*)&smp[c * 16 + (ph << 3) + 4];
      acc[0] += wv * s0.x; acc[1] += wv * s0.y; acc[2] += wv * s0.z; acc[3] += wv * s0.w;
      acc[4] += wv * s1.x; acc[5] += wv * s1.y; acc[6] += wv * s1.z; acc[7] += wv * s1.w;
    }
  }
  const float bias = db[o];
  float* op = out + ((size_t)(n * kO + o)) * kHW + h * kW + w0 + (ph << 3);
#pragma unroll
  for (int j = 0; j < 8; ++j) op[j] = acc[j] + bias;
}

extern "C" void kernel_launch(void* const* d_in, const int* in_sizes, int n_in,
                              void* d_out, int out_size, void* d_ws, size_t ws_size,
                              hipStream_t stream) {
  const float* inp   = (const float*)d_in[0];
  const float* ste_w = (const float*)d_in[1];
  const float* ste_b = (const float*)d_in[2];
  const float* bn_g  = (const float*)d_in[3];
  const float* bn_b  = (const float*)d_in[4];
  const float* bn_m  = (const float*)d_in[5];
  const float* bn_v  = (const float*)d_in[6];
  const float* dw    = (const float*)d_in[7];
  const float* db    = (const float*)d_in[8];
  float* out = (float*)d_out;

  const size_t nhwc_bytes = (size_t)kN * kH * kW * kC * 2;
  const size_t wkb_bytes = (size_t)9 * kO * kC * 2;
  const size_t prm_bytes = (size_t)kN * kH * kW * 3 * 4;
  const size_t need = nhwc_bytes + wkb_bytes + prm_bytes;

  if (ws_size >= need) {
    unsigned short* nhwc = (unsigned short*)d_ws;
    unsigned short* wkb = (unsigned short*)((char*)d_ws + nhwc_bytes);
    float* prm = (float*)((char*)d_ws + nhwc_bytes + wkb_bytes);
    const int reorder_blocks = (9 * kO * kC + 255) / 256;  // 576
    prep_kernel<<<kN * kH + reorder_blocks, 256, 0, stream>>>(
        inp, ste_w, ste_b, bn_g, bn_b, bn_m, bn_v, nhwc, prm, dw, wkb);
    deform_mfma_kernel<<<kN * kH * 2, 512, 0, stream>>>(nhwc, wkb, prm, db, out);
  } else {
    deform_kernel_f32<<<kN * kHW / 16, 256, 0, stream>>>(
        inp, ste_w, ste_b, bn_g, bn_b, bn_m, bn_v, dw, db, out);
  }
}

// Round 13
// 47.640 us; speedup vs baseline: 2.0052x; 1.0213x over previous
//
#include <hip/hip_runtime.h>

constexpr int kN = 8, kC = 128, kH = 64, kW = 64, kO = 128;
constexpr int kHW = kH * kW;
constexpr int kTS = 65;  // padded tile stride (floats) — kills bank conflicts

typedef float f32x4 __attribute__((ext_vector_type(4)));
typedef short bf16x8 __attribute__((ext_vector_type(8)));
typedef unsigned short ushort8 __attribute__((ext_vector_type(8)));

__device__ __forceinline__ float bf2f(unsigned short u) {
  unsigned int x = ((unsigned int)u) << 16;
  return __builtin_bit_cast(float, x);
}
__device__ __forceinline__ unsigned short f2bf(float f) {
  unsigned int b = __builtin_bit_cast(unsigned int, f);
  b += 0x7FFFu + ((b >> 16) & 1u);  // RNE
  return (unsigned short)(b >> 16);
}

#define GLOAD_LDS16(g, l)                                              \
  __builtin_amdgcn_global_load_lds(                                    \
      (const __attribute__((address_space(1))) void*)(g),              \
      (__attribute__((address_space(3))) void*)(l), 16, 0, 0)

// ============================================================================
// prep (+ folded weight reorder): VERBATIM R12 (verified, 48.66 µs).
// ============================================================================
__global__ __launch_bounds__(256) void prep_kernel(
    const float* __restrict__ inp, const float* __restrict__ ste_w,
    const float* __restrict__ ste_b, const float* __restrict__ bn_g,
    const float* __restrict__ bn_b, const float* __restrict__ bn_m,
    const float* __restrict__ bn_v, unsigned short* __restrict__ nhwc,
    float* __restrict__ prm, const float* __restrict__ dw,
    unsigned short* __restrict__ wkb) {
  const int bid = blockIdx.x;
  if (bid >= kN * kH) {  // ---- folded reorder branch (block-uniform) ----
    int idx = (bid - kN * kH) * 256 + threadIdx.x;
    if (idx < 9 * kO * kC) {
      int k = idx / (kO * kC);
      int r = idx - k * (kO * kC);
      int o = r >> 7, c = r & 127;
      int c8 = c >> 3;
      int dstc = ((c8 ^ (o & 7)) << 3) | (c & 7);  // pre-swizzled slot
      wkb[k * (kO * kC) + (o << 7) + dstc] = f2bf(dw[(o * kC + c) * 9 + k]);
    }
    return;
  }

  __shared__ float tile[kC * kTS];    // [c][w] padded, ~33 KB
  __shared__ float part[4][3][kW];    // partial dots
  const int tid = threadIdx.x;
  const int nh = bid;
  const int n = nh >> 6, h = nh & 63;
  const float* base = inp + (size_t)n * kC * kHW + h * kW;

  for (int i = tid; i < kC * kW; i += 256) {
    int c = i >> 6, w = i & 63;
    tile[c * kTS + w] = base[c * kHW + w];
  }
  __syncthreads();

  {
    const int w = tid & 63, cg = tid >> 6;
    float s0 = 0.f, s1 = 0.f, s2 = 0.f;
#pragma unroll 8
    for (int j = 0; j < 32; ++j) {
      int c = cg * 32 + j;
      float v = tile[c * kTS + w];
      s0 += v * ste_w[c];
      s1 += v * ste_w[kC + c];
      s2 += v * ste_w[2 * kC + c];
    }
    part[cg][0][w] = s0;
    part[cg][1][w] = s1;
    part[cg][2][w] = s2;
  }
  __syncthreads();
  if (tid < kW) {
    const int w = tid;
    float s0 = part[0][0][w] + part[1][0][w] + part[2][0][w] + part[3][0][w];
    float s1 = part[0][1][w] + part[1][1][w] + part[2][1][w] + part[3][1][w];
    float s2 = part[0][2][w] + part[1][2][w] + part[2][2][w] + part[3][2][w];
    s0 = (s0 + ste_b[0] - bn_m[0]) * (bn_g[0] * rsqrtf(bn_v[0] + 1e-5f)) + bn_b[0];
    s1 = (s1 + ste_b[1] - bn_m[1]) * (bn_g[1] * rsqrtf(bn_v[1] + 1e-5f)) + bn_b[1];
    s2 = (s2 + ste_b[2] - bn_m[2]) * (bn_g[2] * rsqrtf(bn_v[2] + 1e-5f)) + bn_b[2];
    float th = tanhf(s0) * (3.14f / 6.0f);
    float i1 = tanhf(s1) * 0.75f + 0.75f;
    float i2 = tanhf(s2) * 0.75f + 0.75f;
    float sn = sinf(th), cs = cosf(th);
    prm[nh * 192 + w * 3 + 0] = cs * i1;  // a00
    prm[nh * 192 + w * 3 + 1] = sn;       // sin
    prm[nh * 192 + w * 3 + 2] = cs * i2;  // a11
  }

  // ---- NHWC bf16 write: coalesced (ch fastest across lanes) ----
  for (int i = tid; i < kW * 16; i += 256) {
    int ch = i & 15, w = i >> 4;
    int c0 = ch * 8;
    ushort8 v;
#pragma unroll
    for (int j = 0; j < 8; ++j) v[j] = f2bf(tile[(c0 + j) * kTS + w]);
    *(ushort8*)&nhwc[((size_t)(n * kH + h) * kW + w) * kC + c0] = v;
  }
}

// ============================================================================
// MFMA main kernel: VERBATIM R12 except ONE change — XCD-aware bijective
// blockIdx swizzle (T1). nwg=1024, 8 XCDs: wid = (bid&7)*128 + (bid>>3).
// Default round-robin scatters neighboring rows across XCDs -> per-XCD
// working set = whole 8MB nhwc > 4MB L2 -> 2x over-fetch (R9/R11 FETCH_SIZE
// 21MB vs 10MB ideal). After swizzle each XCD owns exactly one image
// (1MB nhwc + 0.3MB wkb) -> L2-resident gathers.
// ============================================================================
__global__ __launch_bounds__(512, 4) void deform_mfma_kernel(
    const unsigned short* __restrict__ nhwc,
    const unsigned short* __restrict__ wkb,
    const float* __restrict__ prm, const float* __restrict__ db,
    float* __restrict__ out) {
  __shared__ __align__(16) unsigned short As[2][32 * 128];   // 2 x 8 KB
  __shared__ __align__(16) unsigned short Bs[2][128 * 128];  // 2 x 32 KB

  const int tid = threadIdx.x;
  const int lane = tid & 63, wave = tid >> 6;
  // ---- XCD-aware bijective swizzle (nwg = 1024 = 8 * 128) ----
  const int wid = (blockIdx.x & 7) * 128 + (blockIdx.x >> 3);
  const int nh = wid >> 1;
  const int w0 = (wid & 1) << 5;
  const int n = nh >> 6, h = nh & 63;
  const unsigned short* nhwc_n = nhwc + (size_t)n * kH * kW * kC;

  // ---- per-thread A-build assignment & params (p fixed per thread) ----
  const int p = tid >> 4, ch = tid & 15;
  const int cb = ch * 8;
  const float a00 = prm[nh * 192 + (w0 + p) * 3 + 0];
  const float sn  = prm[nh * 192 + (w0 + p) * 3 + 1];
  const float a11 = prm[nh * 192 + (w0 + p) * 3 + 2];

  const int mg = wave >> 2, ng = wave & 3;  // 2 M-groups x 4 N-groups
  const int row = mg * 16 + (lane & 15);
  const int kq = lane >> 4;
  const int rsw = (row & 7) << 4;
  f32x4 acc[2];
  acc[0] = (f32x4){0.f, 0.f, 0.f, 0.f};
  acc[1] = (f32x4){0.f, 0.f, 0.f, 0.f};

  ushort8 aC[4];  // A corners in flight
  float wgt[4];   // bilinear weights in flight

  // ---- B staging: 4 DMA ops/wave, fully linear 32 KB copy ----
  auto issue_B = [&](int k, int buf) {
    const char* gk = (const char*)wkb + (size_t)k * 32768;
    char* lb = (char*)Bs[buf];
    const int wo = wave * 1024;
    const int lo16 = lane * 16;
#pragma unroll
    for (int it = 0; it < 4; ++it) {
      GLOAD_LDS16(gk + it * 8192 + wo + lo16, lb + it * 8192 + wo);
    }
  };

  auto gather_A = [&](int k) {  // R6-verified math
    const float fdy = (float)(k / 3 - 1);
    const float fdx = (float)(k % 3 - 1);
    const float o0 = fdy;
    const float o1 = (k == 2) ? -1.0f : fdx;  // OFF row 2 duplicates row 0
    float y = (float)h + fdy + o0 * a00 + o1 * sn;
    float x = (float)(w0 + p) + fdx - o0 * sn + o1 * a11;
    float y0f = floorf(y), x0f = floorf(x);
    float wy = y - y0f, wx = x - x0f;
    int y0 = (int)y0f, x0 = (int)x0f;
    bool yv0 = (unsigned)y0 < (unsigned)kH;
    bool yv1 = (unsigned)(y0 + 1) < (unsigned)kH;
    bool xv0 = (unsigned)x0 < (unsigned)kW;
    bool xv1 = (unsigned)(x0 + 1) < (unsigned)kW;
    int y0c = min(max(y0, 0), kH - 1);
    int y1c = min(max(y0 + 1, 0), kH - 1);
    int x0c = min(max(x0, 0), kW - 1);
    int x1c = min(max(x0 + 1, 0), kW - 1);
    wgt[0] = (1.f - wy) * (1.f - wx) * (yv0 && xv0 ? 1.f : 0.f);
    wgt[1] = (1.f - wy) * wx * (yv0 && xv1 ? 1.f : 0.f);
    wgt[2] = wy * (1.f - wx) * (yv1 && xv0 ? 1.f : 0.f);
    wgt[3] = wy * wx * (yv1 && xv1 ? 1.f : 0.f);
    aC[0] = *(const ushort8*)&nhwc_n[((y0c * kW) + x0c) * kC + cb];
    aC[1] = *(const ushort8*)&nhwc_n[((y0c * kW) + x1c) * kC + cb];
    aC[2] = *(const ushort8*)&nhwc_n[((y1c * kW) + x0c) * kC + cb];
    aC[3] = *(const ushort8*)&nhwc_n[((y1c * kW) + x1c) * kC + cb];
  };

  auto write_A = [&](int buf) {  // interp -> swizzled As (R6-verified layout)
    ushort8 r;
#pragma unroll
    for (int j = 0; j < 8; ++j) {
      float val = bf2f(aC[0][j]) * wgt[0] + bf2f(aC[1][j]) * wgt[1] +
                  bf2f(aC[2][j]) * wgt[2] + bf2f(aC[3][j]) * wgt[3];
      r[j] = f2bf(val);
    }
    *(ushort8*)((char*)As[buf] + p * 256 + ((ch * 16) ^ ((p & 7) << 4))) = r;
  };

  // ---- prologue: tap 0 ----
  issue_B(0, 0);
  gather_A(0);
  write_A(0);
  __syncthreads();

  // ---- pipelined tap loop: one barrier per tap (R6 structure) ----
  for (int k = 0; k < 9; ++k) {
    const int cur = k & 1;
    if (k < 8) {
      gather_A(k + 1);          // A corners in flight during MFMA
      issue_B(k + 1, cur ^ 1);  // B DMA in flight during MFMA
    }

    const char* Ab = (const char*)As[cur] + row * 256;
    const char* Bb = (const char*)Bs[cur];
#pragma unroll
    for (int ks = 0; ks < 4; ++ks) {
      const int kb = ks * 64 + kq * 16;
      bf16x8 a = *(const bf16x8*)(Ab + (kb ^ rsw));
#pragma unroll
      for (int f = 0; f < 2; ++f) {
        const int orow = (ng * 2 + f) * 16 + (lane & 15);
        bf16x8 b = *(const bf16x8*)(Bb + orow * 256 + (kb ^ ((orow & 7) << 4)));
        acc[f] = __builtin_amdgcn_mfma_f32_16x16x32_bf16(a, b, acc[f], 0, 0, 0);
      }
    }

    if (k < 8) write_A(cur ^ 1);
    __syncthreads();
  }

  // ---- epilogue (round-4 verified mapping) ----
  const int pixb = mg * 16 + (lane >> 4) * 4;
#pragma unroll
  for (int f = 0; f < 2; ++f) {
    const int o = (ng * 2 + f) * 16 + (lane & 15);
    const float bias = db[o];
    float4 v = {acc[f][0] + bias, acc[f][1] + bias, acc[f][2] + bias,
                acc[f][3] + bias};
    *(float4*)&out[((size_t)(n * kO + o)) * kHW + h * kW + w0 + pixb] = v;
  }
}

// ============================================================================
// Fallback (fp32, no workspace) — verbatim.
// ============================================================================
__global__ __launch_bounds__(256) void deform_kernel_f32(
    const float* __restrict__ inp, const float* __restrict__ ste_w,
    const float* __restrict__ ste_b, const float* __restrict__ bn_g,
    const float* __restrict__ bn_b, const float* __restrict__ bn_m,
    const float* __restrict__ bn_v, const float* __restrict__ dw,
    const float* __restrict__ db, float* __restrict__ out) {
  __shared__ __align__(16) float smp[kC * 16];
  __shared__ float prm[16][3];
  const int tid = threadIdx.x;
  const int base = blockIdx.x * 16;
  const int n = base / kHW;
  const int hw = base - n * kHW;
  const int h = hw / kW;
  const int w0 = hw - h * kW;
  const float* inp_n = inp + (size_t)n * kC * kHW;

  for (int i = tid; i < kC * 16; i += 256) {
    int c = i >> 4, p = i & 15;
    smp[i] = inp_n[c * kHW + h * kW + w0 + p];
  }
  __syncthreads();
  {
    const int p = tid >> 4, cl = tid & 15;
    float a0 = 0.f, a1 = 0.f, a2 = 0.f;
#pragma unroll
    for (int i = 0; i < 8; ++i) {
      int c = cl + (i << 4);
      float v = smp[c * 16 + p];
      a0 += v * ste_w[c];
      a1 += v * ste_w[kC + c];
      a2 += v * ste_w[2 * kC + c];
    }
#pragma unroll
    for (int off = 8; off; off >>= 1) {
      a0 += __shfl_down(a0, off, 16);
      a1 += __shfl_down(a1, off, 16);
      a2 += __shfl_down(a2, off, 16);
    }
    if (cl == 0) {
      float s0 = (a0 + ste_b[0] - bn_m[0]) * (bn_g[0] * rsqrtf(bn_v[0] + 1e-5f)) + bn_b[0];
      float s1 = (a1 + ste_b[1] - bn_m[1]) * (bn_g[1] * rsqrtf(bn_v[1] + 1e-5f)) + bn_b[1];
      float s2 = (a2 + ste_b[2] - bn_m[2]) * (bn_g[2] * rsqrtf(bn_v[2] + 1e-5f)) + bn_b[2];
      float th = tanhf(s0) * (3.14f / 6.0f);
      float i1 = tanhf(s1) * 0.75f + 0.75f;
      float i2 = tanhf(s2) * 0.75f + 0.75f;
      prm[p][0] = cosf(th) * i1;
      prm[p][1] = sinf(th);
      prm[p][2] = cosf(th) * i2;
    }
  }
  const int o = tid & 127;
  const int ph = tid >> 7;
  float acc[8] = {0.f};
  for (int k = 0; k < 9; ++k) {
    __syncthreads();
    const float fdy = (float)(k / 3 - 1);
    const float fdx = (float)(k % 3 - 1);
    const float o0 = fdy;
    const float o1 = (k == 2) ? -1.0f : fdx;
    for (int i = tid; i < kC * 16; i += 256) {
      int c = i >> 4, p = i & 15;
      float a00 = prm[p][0], sn = prm[p][1], a11 = prm[p][2];
      float y = (float)h + fdy + o0 * a00 + o1 * sn;
      float x = (float)(w0 + p) + fdx - o0 * sn + o1 * a11;
      float y0f = floorf(y), x0f = floorf(x);
      float wy = y - y0f, wx = x - x0f;
      int y0 = (int)y0f, x0 = (int)x0f;
      const float* ic = inp_n + c * kHW;
      bool yv0 = (unsigned)y0 < (unsigned)kH;
      bool yv1 = (unsigned)(y0 + 1) < (unsigned)kH;
      bool xv0 = (unsigned)x0 < (unsigned)kW;
      bool xv1 = (unsigned)(x0 + 1) < (unsigned)kW;
      int y0c = min(max(y0, 0), kH - 1);
      int y1c = min(max(y0 + 1, 0), kH - 1);
      int x0c = min(max(x0, 0), kW - 1);
      int x1c = min(max(x0 + 1, 0), kW - 1);
      float v00 = (yv0 && xv0) ? ic[y0c * kW + x0c] : 0.f;
      float v01 = (yv0 && xv1) ? ic[y0c * kW + x1c] : 0.f;
      float v10 = (yv1 && xv0) ? ic[y1c * kW + x0c] : 0.f;
      float v11 = (yv1 && xv1) ? ic[y1c * kW + x1c] : 0.f;
      smp[i] = v00 * (1.f - wy) * (1.f - wx) + v01 * (1.f - wy) * wx +
               v10 * wy * (1.f - wx) + v11 * wy * wx;
    }
    __syncthreads();
    const float* wp = dw + (size_t)o * kC * 9 + k;
#pragma unroll 4
    for (int c = 0; c < kC; ++c) {
      float wv = wp[(size_t)c * 9];
      const float4 s0 = *(const float4*)&smp[c * 16 + (ph << 3)];
      const float4 s1 = *(const float4*)&smp[c * 16 + (ph << 3) + 4];
      acc[0] += wv * s0.x; acc[1] += wv * s0.y; acc[2] += wv * s0.z; acc[3] += wv * s0.w;
      acc[4] += wv * s1.x; acc[5] += wv * s1.y; acc[6] += wv * s1.z; acc[7] += wv * s1.w;
    }
  }
  const float bias = db[o];
  float* op = out + ((size_t)(n * kO + o)) * kHW + h * kW + w0 + (ph << 3);
#pragma unroll
  for (int j = 0; j < 8; ++j) op[j] = acc[j] + bias;
}

extern "C" void kernel_launch(void* const* d_in, const int* in_sizes, int n_in,
                              void* d_out, int out_size, void* d_ws, size_t ws_size,
                              hipStream_t stream) {
  const float* inp   = (const float*)d_in[0];
  const float* ste_w = (const float*)d_in[1];
  const float* ste_b = (const float*)d_in[2];
  const float* bn_g  = (const float*)d_in[3];
  const float* bn_b  = (const float*)d_in[4];
  const float* bn_m  = (const float*)d_in[5];
  const float* bn_v  = (const float*)d_in[6];
  const float* dw    = (const float*)d_in[7];
  const float* db    = (const float*)d_in[8];
  float* out = (float*)d_out;

  const size_t nhwc_bytes = (size_t)kN * kH * kW * kC * 2;
  const size_t wkb_bytes = (size_t)9 * kO * kC * 2;
  const size_t prm_bytes = (size_t)kN * kH * kW * 3 * 4;
  const size_t need = nhwc_bytes + wkb_bytes + prm_bytes;

  if (ws_size >= need) {
    unsigned short* nhwc = (unsigned short*)d_ws;
    unsigned short* wkb = (unsigned short*)((char*)d_ws + nhwc_bytes);
    float* prm = (float*)((char*)d_ws + nhwc_bytes + wkb_bytes);
    const int reorder_blocks = (9 * kO * kC + 255) / 256;  // 576
    prep_kernel<<<kN * kH + reorder_blocks, 256, 0, stream>>>(
        inp, ste_w, ste_b, bn_g, bn_b, bn_m, bn_v, nhwc, prm, dw, wkb);
    deform_mfma_kernel<<<kN * kH * 2, 512, 0, stream>>>(nhwc, wkb, prm, db, out);
  } else {
    deform_kernel_f32<<<kN * kHW / 16, 256, 0, stream>>>(
        inp, ste_w, ste_b, bn_g, bn_b, bn_m, bn_v, dw, db, out);
  }
}